// Round 6
// baseline (416.240 us; speedup 1.0000x reference)
//
#include <hip/hip_runtime.h>
#include <hip/hip_bf16.h>

#define D 128
#define SCAN_C 512
#define BKT 512        // nodes per bucket
#define BKT_SHIFT 9
#define CH 256         // edge chunks
#define NBMAX 512
#define MREP 64        // min-buffer replicas

typedef __attribute__((ext_vector_type(8))) short bf16x8;
typedef __attribute__((ext_vector_type(4))) float f32x4;

// ---------------- bf16 helpers (manual, RN-even) ----------------
__device__ __forceinline__ float bf16_to_f(unsigned int u) {
    union { unsigned int i; float f; } c; c.i = u << 16; return c.f;
}
__device__ __forceinline__ unsigned short f_to_bf16(float f) {
    union { float f; unsigned int i; } c; c.f = f;
    unsigned int r = c.i + 0x7FFFu + ((c.i >> 16) & 1u);
    return (unsigned short)(r >> 16);
}

__device__ __forceinline__ int load_idx(const void* p, long long i, int is64) {
    if (is64) return (int)((const long long*)p)[i];
    return ((const int*)p)[i];
}

// ---------------- wave-parallel dtype detection (runs inline in any block) ----------------
__device__ __forceinline__ void detect_inline(const void* x0, const void* eidx,
                                              int* is_bf16_out, int* is64_out) {
    const unsigned short* xr = (const unsigned short*)x0;
    const int* er = (const int*)eidx;
    const int lane = threadIdx.x & 63;
    unsigned short u = xr[2 * lane];
    int e = (u >> 7) & 0xFF;
    unsigned long long pm = __ballot(e >= 0x74 && e <= 0x82);
    *is_bf16_out = (__popcll(pm) >= 32) ? 1 : 0;
    unsigned long long zm = __ballot(er[1 + 2 * lane] == 0);
    *is64_out = (__popcll(zm) >= 60) ? 1 : 0;
}

// ---------------- merged setup: detect + cvt_x + cvt_f + packW + bucket hist ----------------
// Role by blockIdx: [0,2048) cvt_x, [2048,2048+CH) hist, [2048+CH] cvt_f, rest packW.
// Each block recomputes the flag locally (192 cached loads, wave-parallel) -> no
// cross-block dependency; block 0 also publishes flag for downstream kernels.
__global__ __launch_bounds__(256)
void setup_kernel(const void* __restrict__ x0, const void* __restrict__ eidx,
                  const void* __restrict__ Wl0, const void* __restrict__ Wr0,
                  const void* __restrict__ bl0,
                  int* __restrict__ flag, unsigned short* __restrict__ xb,
                  float* __restrict__ blf, unsigned short* __restrict__ Wpack,
                  int* __restrict__ counts2D, int N, int E, int L, int NB, int EPC) {
    __shared__ int hist[NBMAX];
    int is_bf16, is64;
    detect_inline(x0, eidx, &is_bf16, &is64);
    const int b = blockIdx.x;
    const int t = threadIdx.x;
    if (b == 0 && t == 0) { flag[0] = is64; flag[1] = is_bf16; }

    if (b < 2048) {                       // cvt_x
        if (!is_bf16) {
            const float* s = (const float*)x0;
            const int n = N * D;
            for (int i = b * 256 + t; i < n; i += 2048 * 256) xb[i] = f_to_bf16(s[i]);
        }
        return;
    }
    if (b < 2048 + CH) {                  // bucket hist
        const int c = b - 2048;
        for (int i = t; i < NB; i += 256) hist[i] = 0;
        __syncthreads();
        const int end = min(E, (c + 1) * EPC);
        for (int e = c * EPC + t; e < end; e += 256) {
            int d = load_idx(eidx, (long long)E + e, is64);
            atomicAdd(&hist[d >> BKT_SHIFT], 1);
        }
        __syncthreads();
        for (int i = t; i < NB; i += 256) counts2D[i * CH + c] = hist[i];
        return;
    }
    if (b == 2048 + CH) {                 // cvt_f (bias)
        const int n = L * D;
        if (is_bf16) {
            const unsigned short* s = (const unsigned short*)bl0;
            for (int i = t; i < n; i += 256) blf[i] = bf16_to_f(s[i]);
        } else {
            const float* s = (const float*)bl0;
            for (int i = t; i < n; i += 256) blf[i] = s[i];
        }
        return;
    }
    // packW
    {
        int idx = (b - (2048 + CH + 1)) * 256 + t;
        if (idx >= L * 8 * 8 * 64) return;
        int lane = idx & 63;
        int ks = (idx >> 6) & 7;
        int nt = (idx >> 9) & 7;
        int layer = idx >> 12;
        int n = nt * 16 + (lane & 15);
        int k0 = ks * 32 + (lane >> 4) * 8;
        unsigned short outv[8];
#pragma unroll
        for (int j = 0; j < 8; ++j) {
            int k = k0 + j;
            size_t off = (size_t)layer * D * D + (size_t)n * D + (k & 127);
            float v;
            if (is_bf16) {
                const unsigned short* W = (const unsigned short*)((k < D) ? Wl0 : Wr0);
                v = bf16_to_f(W[off]);
            } else {
                const float* W = (const float*)((k < D) ? Wl0 : Wr0);
                v = W[off];
            }
            outv[j] = f_to_bf16(v);
        }
        *(uint4*)&Wpack[(size_t)idx * 8] = *(uint4*)outv;
    }
}

// ---------------- scans (unchanged, known-good) ----------------
__global__ void gscan1_kernel(const int* __restrict__ in, int* __restrict__ blockSums, int n) {
    __shared__ int red[256];
    int base = blockIdx.x * SCAN_C;
    int t = threadIdx.x;
    int s = 0;
    if (base + t < n) s += in[base + t];
    if (base + t + 256 < n) s += in[base + t + 256];
    red[t] = s;
    __syncthreads();
    for (int off = 128; off > 0; off >>= 1) {
        if (t < off) red[t] += red[t + off];
        __syncthreads();
    }
    if (t == 0) blockSums[blockIdx.x] = red[0];
}

__global__ void gscan2_kernel(int* __restrict__ blockSums, int nb) {
    __shared__ int sh[256];
    int t = threadIdx.x;
    int orig = (t < nb) ? blockSums[t] : 0;
    sh[t] = orig;
    __syncthreads();
    for (int off = 1; off < 256; off <<= 1) {
        int v = (t >= off) ? sh[t - off] : 0;
        __syncthreads();
        sh[t] += v;
        __syncthreads();
    }
    if (t < nb) blockSums[t] = sh[t] - orig;
}

__global__ void gscan3_kernel(const int* __restrict__ in, const int* __restrict__ blockBase,
                              int* __restrict__ out, int n) {
    __shared__ int sh[SCAN_C];
    int base = blockIdx.x * SCAN_C;
    int t = threadIdx.x;
    int v0 = (base + t < n) ? in[base + t] : 0;
    int v1 = (base + t + 256 < n) ? in[base + t + 256] : 0;
    sh[t] = v0;
    sh[t + 256] = v1;
    __syncthreads();
    for (int off = 1; off < SCAN_C; off <<= 1) {
        int a = (t >= off) ? sh[t - off] : 0;
        int b = (t + 256 >= off) ? sh[t + 256 - off] : 0;
        __syncthreads();
        sh[t] += a;
        sh[t + 256] += b;
        __syncthreads();
    }
    int bb = blockBase[blockIdx.x];
    if (base + t < n) out[base + t] = bb + sh[t] - v0;
    if (base + t + 256 < n) out[base + t + 256] = bb + sh[t + 256] - v1;
}

__global__ void bucket_scatter_kernel(const void* __restrict__ eidx, const int* __restrict__ flag,
                                      const int* __restrict__ bases2D, unsigned int* __restrict__ ebuf,
                                      int E, int NB, int EPC) {
    __shared__ int cur[NBMAX];
    int c = blockIdx.x;
    for (int i = threadIdx.x; i < NB; i += blockDim.x) cur[i] = bases2D[i * CH + c];
    __syncthreads();
    int is64 = flag[0];
    int end = min(E, (c + 1) * EPC);
    for (int e = c * EPC + threadIdx.x; e < end; e += blockDim.x) {
        int s = load_idx(eidx, e, is64);
        int d = load_idx(eidx, (long long)E + e, is64);
        int b = d >> BKT_SHIFT;
        int pos = atomicAdd(&cur[b], 1);
        ebuf[pos] = ((unsigned)s << BKT_SHIFT) | (unsigned)(d & (BKT - 1));
    }
}

__global__ __launch_bounds__(BKT)
void bucket_csr_kernel(const unsigned int* __restrict__ ebuf, const int* __restrict__ bases2D,
                       int* __restrict__ offsets, int* __restrict__ srcs, int E, int N, int NB) {
    __shared__ int lcnt[BKT];
    __shared__ int sh[BKT];
    __shared__ int lcur[BKT];
    int b = blockIdx.x;
    int t = threadIdx.x;
    int start = bases2D[b * CH];
    int end = (b + 1 < NB) ? bases2D[(b + 1) * CH] : E;
    lcnt[t] = 0;
    __syncthreads();
    for (int e = start + t; e < end; e += BKT)
        atomicAdd(&lcnt[ebuf[e] & (BKT - 1)], 1);
    __syncthreads();
    sh[t] = lcnt[t];
    __syncthreads();
    for (int off = 1; off < BKT; off <<= 1) {
        int v = (t >= off) ? sh[t - off] : 0;
        __syncthreads();
        sh[t] += v;
        __syncthreads();
    }
    int excl = sh[t] - lcnt[t];
    int node = b * BKT + t;
    if (node < N) offsets[node] = start + excl;
    lcur[t] = start + excl;
    __syncthreads();
    for (int e = start + t; e < end; e += BKT) {
        unsigned int p = ebuf[e];
        int pos = atomicAdd(&lcur[p & (BKT - 1)], 1);
        srcs[pos] = (int)(p >> BKT_SHIFT);
    }
    if (b == 0 && t == 0) offsets[N] = E;
}

// ---------------- fused agg + dual MFMA GEMM, 64-row tile ----------------
// Block = 256 thr (4 waves), 64 rows, grid = ceil(N/64).
// Phase A: r5's verified 8-deep gather loop (16-lane group per row, 4 rows/group),
//   mean -> Mt LDS (r3-verified chunk-XOR swizzle). No meanb HBM round-trip and no
//   kernel-boundary dirty-L2 flush of it.
// Phase B: rotating 8 KB W ks-slice in LDS (r3-verified), A-frags from Mt/global.
// LDS = Mt 17.4K + Ws 8K + smin 2K = 27.6K -> 5 blocks/CU = 20 waves/CU; r5 showed
// 14.4 waves/CU already sustains the 3.55 TB/s gather ceiling.
__global__ __launch_bounds__(256)
void fused_sage_kernel(const unsigned short* __restrict__ xmain,
                       const unsigned short* __restrict__ xalt,
                       const int* __restrict__ flag,
                       const int* __restrict__ offsets,
                       const int* __restrict__ srcs,
                       const unsigned short* __restrict__ Wpack,
                       const float* __restrict__ bl,
                       unsigned short* __restrict__ outb,
                       unsigned int* __restrict__ minbuf,
                       int N, int relu, int do_min) {
    __shared__ unsigned short Mt[64][136];    // mean tile; aliased as Otile in epilogue
    __shared__ unsigned short Ws[8 * 64 * 8]; // one W ks-slice (8 KB)
    __shared__ float smin[4][D];

    const unsigned short* xb = flag[1] ? xalt : xmain;
    const uint4* xp = (const uint4*)xb;
    const int tid = threadIdx.x;
    const int node0 = blockIdx.x * 64;

    // ---- Phase A: gather + mean into Mt (r5 inner loop) ----
    {
        const int g  = tid >> 4;   // 0..15
        const int gl = tid & 15;
#pragma unroll 1
        for (int i = 0; i < 4; ++i) {
            const int row = g * 4 + i;          // 0..63
            const int node = node0 + row;
            float acc[8];
#pragma unroll
            for (int q = 0; q < 8; ++q) acc[q] = 0.f;
            int beg = 0, end = 0;
            if (node < N) { beg = offsets[node]; end = offsets[node + 1]; }

#define ACC8(v)                                                              \
    acc[0] += bf16_to_f((v).x & 0xFFFFu); acc[1] += bf16_to_f((v).x >> 16);  \
    acc[2] += bf16_to_f((v).y & 0xFFFFu); acc[3] += bf16_to_f((v).y >> 16);  \
    acc[4] += bf16_to_f((v).z & 0xFFFFu); acc[5] += bf16_to_f((v).z >> 16);  \
    acc[6] += bf16_to_f((v).w & 0xFFFFu); acc[7] += bf16_to_f((v).w >> 16);

            int j = beg;
            for (; j + 7 < end; j += 8) {
                int s0 = srcs[j];     int s1 = srcs[j + 1];
                int s2 = srcs[j + 2]; int s3 = srcs[j + 3];
                int s4 = srcs[j + 4]; int s5 = srcs[j + 5];
                int s6 = srcs[j + 6]; int s7 = srcs[j + 7];
                uint4 v0 = xp[(size_t)s0 * 16 + gl];
                uint4 v1 = xp[(size_t)s1 * 16 + gl];
                uint4 v2 = xp[(size_t)s2 * 16 + gl];
                uint4 v3 = xp[(size_t)s3 * 16 + gl];
                uint4 v4 = xp[(size_t)s4 * 16 + gl];
                uint4 v5 = xp[(size_t)s5 * 16 + gl];
                uint4 v6 = xp[(size_t)s6 * 16 + gl];
                uint4 v7 = xp[(size_t)s7 * 16 + gl];
                ACC8(v0); ACC8(v1); ACC8(v2); ACC8(v3);
                ACC8(v4); ACC8(v5); ACC8(v6); ACC8(v7);
            }
            if (j + 3 < end) {
                int s0 = srcs[j];     int s1 = srcs[j + 1];
                int s2 = srcs[j + 2]; int s3 = srcs[j + 3];
                uint4 v0 = xp[(size_t)s0 * 16 + gl];
                uint4 v1 = xp[(size_t)s1 * 16 + gl];
                uint4 v2 = xp[(size_t)s2 * 16 + gl];
                uint4 v3 = xp[(size_t)s3 * 16 + gl];
                ACC8(v0); ACC8(v1); ACC8(v2); ACC8(v3);
                j += 4;
            }
            for (; j < end; ++j) {
                uint4 v = xp[(size_t)srcs[j] * 16 + gl];
                ACC8(v);
            }
#undef ACC8

            float inv = (end > beg) ? 1.0f / (float)(end - beg) : 0.f;
            uint4 o;
            o.x = (unsigned)f_to_bf16(acc[0] * inv) | ((unsigned)f_to_bf16(acc[1] * inv) << 16);
            o.y = (unsigned)f_to_bf16(acc[2] * inv) | ((unsigned)f_to_bf16(acc[3] * inv) << 16);
            o.z = (unsigned)f_to_bf16(acc[4] * inv) | ((unsigned)f_to_bf16(acc[5] * inv) << 16);
            o.w = (unsigned)f_to_bf16(acc[6] * inv) | ((unsigned)f_to_bf16(acc[7] * inv) << 16);
            // chunk-XOR swizzle: logical 16B chunk gl stored at gl ^ (row&15)
            *(uint4*)&Mt[row][(gl ^ (row & 15)) << 3] = o;
        }
    }
    __syncthreads();

    // ---- Phase B: dual GEMM ----
    const int wave = tid >> 6;            // 0..3
    const int lane = tid & 63;
    const int m16 = lane & 15;
    const int quad = lane >> 4;
    const int arow = node0 + wave * 16 + m16;
    const bool rvalid = arow < N;
    const uint4* wsrc = (const uint4*)Wpack;
    uint4* Wsv = (uint4*)Ws;

    f32x4 acc2[8];
#pragma unroll
    for (int i = 0; i < 8; ++i) acc2[i] = (f32x4)0.0f;

    for (int ks = 0; ks < 8; ++ks) {
        // stage this ks-slice: 512 uint4, 2 per thread ([nt][lane] layout)
        uint4 w0 = wsrc[((tid >> 6) * 8 + ks) * 64 + (tid & 63)];
        uint4 w1 = wsrc[(((tid >> 6) + 4) * 8 + ks) * 64 + (tid & 63)];
        bf16x8 afrag;
        if (ks < 4) {
            afrag = *(bf16x8*)&Mt[wave * 16 + m16][((ks * 4 + quad) ^ m16) << 3];
        } else {
            uint4 tmp = make_uint4(0u, 0u, 0u, 0u);
            if (rvalid) tmp = *(const uint4*)(xb + (size_t)arow * D + (ks - 4) * 32 + quad * 8);
            afrag = *(bf16x8*)&tmp;
        }
        Wsv[tid] = w0;
        Wsv[tid + 256] = w1;
        __syncthreads();
#pragma unroll
        for (int nt = 0; nt < 8; ++nt) {
            bf16x8 bfrag = *(const bf16x8*)&Ws[(nt * 64 + lane) << 3];
            acc2[nt] = __builtin_amdgcn_mfma_f32_16x16x32_bf16(afrag, bfrag, acc2[nt], 0, 0, 0);
        }
        __syncthreads();
    }

    if (do_min) {
#pragma unroll
        for (int nt = 0; nt < 8; ++nt) {
            int n = nt * 16 + m16;
            float b = bl[n];
            float m = 3.402823466e38f;
#pragma unroll
            for (int r = 0; r < 4; ++r) {
                int node = node0 + wave * 16 + quad * 4 + r;
                float v = (node < N) ? (acc2[nt][r] + b) : 3.402823466e38f;
                m = fminf(m, v);
            }
            m = fminf(m, __shfl_xor(m, 16, 64));
            m = fminf(m, __shfl_xor(m, 32, 64));
            if (quad == 0) smin[wave][n] = m;
        }
        __syncthreads();
        if (tid < D) {
            float m = fminf(fminf(smin[0][tid], smin[1][tid]), fminf(smin[2][tid], smin[3][tid]));
            unsigned bits = __float_as_uint(m);
            unsigned enc = ((int)bits >= 0) ? (bits ^ 0x80000000u) : ~bits;
            atomicMin(&minbuf[(blockIdx.x & (MREP - 1)) * D + tid], enc);
        }
        return;
    }

    // epilogue: Mt reads all done (loop-final barrier) -> alias as Otile
    {
        unsigned short (*Ot)[136] = Mt;
#pragma unroll
        for (int nt = 0; nt < 8; ++nt) {
            int n = nt * 16 + m16;
            float b = bl[n];
#pragma unroll
            for (int r = 0; r < 4; ++r) {
                int m = wave * 16 + quad * 4 + r;
                float v = acc2[nt][r] + b;
                if (relu) v = fmaxf(v, 0.f);
                Ot[m][n] = f_to_bf16(v);
            }
        }
        __syncthreads();
        for (int i = tid; i < 64 * 16; i += 256) {
            int row = i >> 4;
            int c = i & 15;
            int n = node0 + row;
            if (n < N) ((uint4*)outb)[(size_t)n * 16 + c] = *(uint4*)&Ot[row][c * 8];
        }
    }
}

// ---------------- decode fused min (parallel replica fold) ----------------
__global__ void min_out_kernel(const unsigned int* __restrict__ minbuf,
                               const int* __restrict__ flag, void* __restrict__ out) {
    __shared__ unsigned int sh[4][D];
    int tid = threadIdx.x;             // 512 threads
    int q = tid >> 7;
    int c = tid & 127;
    unsigned u = 0xFFFFFFFFu;
    for (int r = q; r < MREP; r += 4) u = min(u, minbuf[r * D + c]);
    sh[q][c] = u;
    __syncthreads();
    if (tid < D) {
        unsigned m = min(min(sh[0][tid], sh[1][tid]), min(sh[2][tid], sh[3][tid]));
        unsigned i = (m & 0x80000000u) ? (m ^ 0x80000000u) : ~m;
        union { unsigned i; float f; } cv; cv.i = i;
        if (flag[1]) ((unsigned short*)out)[tid] = f_to_bf16(cv.f);
        else         ((float*)out)[tid] = cv.f;
    }
}

// ---------------- launch ----------------
extern "C" void kernel_launch(void* const* d_in, const int* in_sizes, int n_in,
                              void* d_out, int out_size, void* d_ws, size_t ws_size,
                              hipStream_t stream) {
    const void* x0   = d_in[0];
    const void* eidx = d_in[1];
    const void* Wl0  = d_in[2];
    const void* bl0  = d_in[3];
    const void* Wr0  = d_in[4];

    const int N = in_sizes[0] / D;          // 100000
    const int E = in_sizes[1] / 2;          // 1600000
    const int L = in_sizes[2] / (D * D);    // 3

    char* ws = (char*)d_ws;
    size_t off = 0;
    auto alloc = [&](size_t bytes) -> void* {
        void* p = ws + off;
        off += (bytes + 255) & ~(size_t)255;
        return p;
    };
    unsigned short* xb    = (unsigned short*)alloc((size_t)N * D * 2);
    unsigned short* bufA  = (unsigned short*)alloc((size_t)N * D * 2);
    unsigned short* scratch = (unsigned short*)alloc((size_t)N * D * 2);   // ebuf home
    int*   offsets = (int*)alloc((size_t)(N + 1) * sizeof(int));
    int*   srcs    = (int*)alloc((size_t)E * sizeof(int));
    int*   flag    = (int*)alloc(256);
    unsigned short* Wpack = (unsigned short*)alloc((size_t)L * 8 * 8 * 64 * 8 * 2);
    float* blf     = (float*)alloc((size_t)L * D * sizeof(float));
    unsigned int* minbuf = (unsigned int*)alloc((size_t)MREP * D * sizeof(unsigned int));
    int* counts2D  = (int*)alloc((size_t)NBMAX * CH * sizeof(int));
    int* bases2D   = (int*)alloc((size_t)NBMAX * CH * sizeof(int));
    int* blockSums = (int*)alloc(1024 * sizeof(int));
    (void)ws_size; (void)n_in; (void)out_size;

    const int NB  = (N + BKT - 1) / BKT;     // 196
    const int EPC = (E + CH - 1) / CH;       // 6250
    const int n2  = NB * CH;                 // 50176
    unsigned int* ebuf = (unsigned int*)scratch;   // not live during layer loop

    const int PACKW_BLOCKS = (L * 8 * 8 * 64 + 255) / 256;           // 48
    setup_kernel<<<2048 + CH + 1 + PACKW_BLOCKS, 256, 0, stream>>>(
        x0, eidx, Wl0, Wr0, bl0, flag, xb, blf, Wpack, counts2D, N, E, L, NB, EPC);

    hipMemsetAsync(minbuf, 0xFF, (size_t)MREP * D * sizeof(unsigned int), stream);

    const int nb2 = (n2 + SCAN_C - 1) / SCAN_C;
    gscan1_kernel<<<nb2, 256, 0, stream>>>(counts2D, blockSums, n2);
    gscan2_kernel<<<1, 256, 0, stream>>>(blockSums, nb2);
    gscan3_kernel<<<nb2, 256, 0, stream>>>(counts2D, blockSums, bases2D, n2);
    bucket_scatter_kernel<<<CH, 256, 0, stream>>>(eidx, flag, bases2D, ebuf, E, NB, EPC);
    bucket_csr_kernel<<<NB, BKT, 0, stream>>>(ebuf, bases2D, offsets, srcs, E, N, NB);

    const unsigned short* cur     = xb;                        // fp32 path: converted copy
    const unsigned short* cur_alt = (const unsigned short*)x0; // bf16 path: raw input
    unsigned short* nxt = bufA;
    for (int l = 0; l < L; ++l) {
        int last = (l == L - 1);
        fused_sage_kernel<<<(N + 63) / 64, 256, 0, stream>>>(
            cur, cur_alt, flag, offsets, srcs,
            Wpack + (size_t)l * 8 * 8 * 64 * 8, blf + (size_t)l * D,
            nxt, minbuf, N, last ? 0 : 1, last);
        cur = nxt; cur_alt = nxt;
        nxt = (nxt == bufA) ? xb : bufA;
    }

    min_out_kernel<<<1, 512, 0, stream>>>(minbuf, flag, (void*)d_out);
}